// Round 2
// baseline (1011.671 us; speedup 1.0000x reference)
//
#include <hip/hip_runtime.h>
#include <math.h>

#define N_NODES 4096
#define IN_DIM  512
#define H_DIM   256
#define OUT_DIM 64
#define SCAD_Af 3.7f
#define EPSf    1e-8f
#define NBINS   16384
#define MAXE    524288
#define MAXD    256

// ---------------------------------------------------------------------------
// Fused: degree + column capture in ONE pass over A.
// tmpcols[i*MAXD + p] = j for each nonzero (order within row irrelevant).
__global__ void k_degfill(const float* __restrict__ A, int* __restrict__ tmpcols,
                          int* __restrict__ rowcnt, float* __restrict__ D,
                          float* __restrict__ isD) {
    int i = blockIdx.x;
    __shared__ int cnt;
    if (threadIdx.x == 0) cnt = 0;
    __syncthreads();
    const float* row = A + (size_t)i * N_NODES;
    for (int j = threadIdx.x; j < N_NODES; j += blockDim.x) {
        if (row[j] != 0.0f) {
            int p = atomicAdd(&cnt, 1);
            if (p < MAXD) tmpcols[i * MAXD + p] = j;
        }
    }
    __syncthreads();
    if (threadIdx.x == 0) {
        int t = cnt;                 // degree (mathematically << MAXD)
        rowcnt[i] = t;
        float d = (float)t + 1.0f;   // add_loops
        D[i] = d;
        isD[i] = 1.0f / sqrtf(d);
    }
}

// Exclusive scan of 4096 ints -> rowptr[0..4096]. Single block, 1024 threads.
__global__ void k_scan(const int* __restrict__ rowcnt, int* __restrict__ rowptr) {
    __shared__ int sh[1024];
    int t = threadIdx.x;
    int v0 = rowcnt[4 * t + 0], v1 = rowcnt[4 * t + 1];
    int v2 = rowcnt[4 * t + 2], v3 = rowcnt[4 * t + 3];
    int s = v0 + v1 + v2 + v3;
    sh[t] = s;
    __syncthreads();
    for (int off = 1; off < 1024; off <<= 1) {
        int x = 0;
        if (t >= off) x = sh[t - off];
        __syncthreads();
        sh[t] += x;
        __syncthreads();
    }
    int excl = sh[t] - s;
    rowptr[4 * t + 0] = excl;
    rowptr[4 * t + 1] = excl + v0;
    rowptr[4 * t + 2] = excl + v0 + v1;
    rowptr[4 * t + 3] = excl + v0 + v1 + v2;
    if (t == 1023) rowptr[N_NODES] = sh[1023];
}

// Compact tmpcols -> dense CSR colIdx.
__global__ void k_compact(const int* __restrict__ tmpcols, const int* __restrict__ rowcnt,
                          const int* __restrict__ rowptr, int* __restrict__ colIdx) {
    int i = blockIdx.x;
    int n = rowcnt[i], base = rowptr[i];
    for (int p = threadIdx.x; p < n; p += blockDim.x)
        colIdx[base + p] = tmpcols[i * MAXD + p];
}

// ---------------------------------------------------------------------------
// fp32 tiled GEMM: C[M,Nn] = act(Am[M,K] @ Bm[K,Nn] + bias). BM=BN=64, BK=16.
template <int Nn, int K, bool RELU>
__global__ void k_gemm(const float* __restrict__ Am, const float* __restrict__ Bm,
                       const float* __restrict__ bias, float* __restrict__ Cm) {
    __shared__ float As[16][68];
    __shared__ float Bs[16][64];
    int tx = threadIdx.x & 15, ty = threadIdx.x >> 4;
    int bm = blockIdx.y * 64, bn = blockIdx.x * 64;
    float acc[4][4] = {};
    for (int k0 = 0; k0 < K; k0 += 16) {
        {
            int r = threadIdx.x >> 2, kv = threadIdx.x & 3;
            float4 v = *(const float4*)(Am + (size_t)(bm + r) * K + k0 + kv * 4);
            As[kv * 4 + 0][r] = v.x;
            As[kv * 4 + 1][r] = v.y;
            As[kv * 4 + 2][r] = v.z;
            As[kv * 4 + 3][r] = v.w;
        }
        {
            int kk = threadIdx.x >> 4, nv = threadIdx.x & 15;
            *(float4*)&Bs[kk][nv * 4] =
                *(const float4*)(Bm + (size_t)(k0 + kk) * Nn + bn + nv * 4);
        }
        __syncthreads();
#pragma unroll
        for (int kk = 0; kk < 16; kk++) {
            float a[4], b[4];
#pragma unroll
            for (int u = 0; u < 4; u++) { a[u] = As[kk][ty * 4 + u]; b[u] = Bs[kk][tx * 4 + u]; }
#pragma unroll
            for (int u = 0; u < 4; u++)
#pragma unroll
                for (int v = 0; v < 4; v++) acc[u][v] += a[u] * b[v];
        }
        __syncthreads();
    }
#pragma unroll
    for (int u = 0; u < 4; u++) {
        int m = bm + ty * 4 + u;
#pragma unroll
        for (int v = 0; v < 4; v++) {
            int n = bn + tx * 4 + v;
            float x = acc[u][v] + bias[n];
            if (RELU) x = fmaxf(x, 0.0f);
            Cm[(size_t)m * Nn + n] = x;
        }
    }
}

// ---------------------------------------------------------------------------
// Row-normalize + zero the histogram (piggyback: saves a memset launch).
__global__ void k_norm(const float* __restrict__ Fc, const float* __restrict__ isD,
                       float* __restrict__ Fu, unsigned int* __restrict__ hist) {
    int gid = blockIdx.x * blockDim.x + threadIdx.x;
    if (gid < NBINS) hist[gid] = 0u;
    int i = gid >> 6, c = gid & 63;
    float fn = Fc[(size_t)i * 64 + c] * isD[i];
    float s = fn * fn;
    for (int off = 32; off; off >>= 1) s += __shfl_xor(s, off, 64);
    float nrm = sqrtf(s);
    Fu[(size_t)i * 64 + c] = fn / fmaxf(nrm, EPSf);
}

// Edge cosine distances, wave-per-row (lane = channel). Coalesced everywhere.
__global__ void k_edge(const float* __restrict__ Fu, const int* __restrict__ rowptr,
                       const int* __restrict__ colIdx,
                       float* __restrict__ y_e, unsigned int* __restrict__ hist) {
    int gid = blockIdx.x * blockDim.x + threadIdx.x;
    int i = gid >> 6, c = gid & 63;
    int e0 = rowptr[i], e1 = rowptr[i + 1];
    float fi = Fu[(size_t)i * 64 + c];
    for (int base = e0; base < e1; base += 64) {
        int m = e1 - base; if (m > 64) m = 64;
        int jl = (c < m) ? colIdx[base + c] : 0;   // coalesced chunk of indices
        float ylane = 0.0f;
        for (int t = 0; t < m; t++) {
            int j = __shfl(jl, t, 64);
            float v = fi * Fu[(size_t)j * 64 + c]; // coalesced 256B row load
#pragma unroll
            for (int off = 32; off; off >>= 1) v += __shfl_xor(v, off, 64);
            float y = 1.0f - v;
            y = fminf(fmaxf(y, 0.0f), 2.0f);
            if (t == c) ylane = y;                 // stage for coalesced store
        }
        if (c < m) {
            y_e[base + c] = ylane;
            int bin = (int)(ylane * (NBINS * 0.5f));
            if (bin > NBINS - 1) bin = NBINS - 1;
            atomicAdd(&hist[bin], 1u);
        }
    }
}

// Histogram rank-select of the 0.75 nanquantile + lam_combined scalar.
__global__ void k_quant(const unsigned int* __restrict__ hist,
                        const int* __restrict__ rowptr,
                        const float* __restrict__ lg0, const float* __restrict__ rdec,
                        const float* __restrict__ ralpha, int kiter,
                        float* __restrict__ scal) {
    __shared__ unsigned int psum[1024];
    __shared__ float vv[2];
    int t = threadIdx.x;
    const uint4* h4 = (const uint4*)hist;
    unsigned int s = 0;
#pragma unroll
    for (int q = 0; q < 4; q++) {
        uint4 v = h4[t * 4 + q];
        s += v.x + v.y + v.z + v.w;
    }
    psum[t] = s;
    __syncthreads();
    for (int off = 1; off < 1024; off <<= 1) {
        unsigned int x = 0;
        if (t >= off) x = psum[t - off];
        __syncthreads();
        psum[t] += x;
        __syncthreads();
    }
    int nE = rowptr[N_NODES];
    double h = 0.75 * (double)(nE - 1);
    long long i0 = (long long)h;
    float frac = (float)(h - (double)i0);
    unsigned int r0 = (unsigned int)i0, r1 = (unsigned int)(i0 + 1);
    unsigned int cum = (t == 0) ? 0u : psum[t - 1];
    for (int b = 0; b < 16; b++) {
        unsigned int cn = hist[t * 16 + b];
        unsigned int lo = cum;
        cum += cn;
        if (cn) {
            float v = ((float)(t * 16 + b) + 0.5f) * (2.0f / (float)NBINS);
            if (lo <= r0 && r0 < cum) vv[0] = v;
            if (lo <= r1 && r1 < cum) vv[1] = v;
        }
    }
    __syncthreads();
    if (t == 0) {
        float gd = vv[0] + frac * (vv[1] - vv[0]);
        gd = fmaxf(gd, EPSf);
        float alpha = 1.0f / (1.0f + expf(-ralpha[0]));
        float g0 = expf(lg0[0]);
        float r = 1.0f / (1.0f + expf(-rdec[0]));
        float gp = g0;
        for (int q = 0; q < kiter; q++) gp *= r;
        scal[0] = alpha * (gp / SCAD_Af) + (1.0f - alpha) * (gd / SCAD_Af);
    }
}

// Sparse propagation, wave-per-row (lane = channel), chunked coalesced staging.
__global__ void k_prop(const int* __restrict__ rowptr, const int* __restrict__ colIdx,
                       const float* __restrict__ y_e, const float* __restrict__ Fc,
                       const float* __restrict__ F0, const float* __restrict__ D,
                       const float* __restrict__ isD, const float* __restrict__ scal,
                       float* __restrict__ Fout) {
    int gid = blockIdx.x * blockDim.x + threadIdx.x;
    int i = gid >> 6, c = gid & 63;
    float lamc = scal[0];
    const float lam = (float)(1.0 / 0.9 - 1.0);
    int e0 = rowptr[i], e1 = rowptr[i + 1];
    float acc = 0.0f, wsum = 0.0f;
    for (int base = e0; base < e1; base += 64) {
        int m = e1 - base; if (m > 64) m = 64;
        int   jl = (c < m) ? colIdx[base + c] : 0;
        float yl = (c < m) ? y_e[base + c] : 9.0f;
        float il = (c < m) ? isD[jl] : 0.0f;
        for (int t = 0; t < m; t++) {
            int   j    = __shfl(jl, t, 64);
            float y    = __shfl(yl, t, 64);
            float isdj = __shfl(il, t, 64);
            float w;
            if (y <= lamc) w = 1.0f;
            else if (y <= SCAD_Af * lamc)
                w = (SCAD_Af * lamc - y) / ((SCAD_Af - 1.0f) * fmaxf(y, EPSf));
            else w = 0.0f;
            wsum += w;
            acc += (w * isdj) * Fc[(size_t)j * 64 + c];
        }
    }
    float isdi = isD[i];
    float Q = wsum / D[i] + lam;
    Fout[(size_t)i * 64 + c] = (isdi * acc + lam * F0[(size_t)i * 64 + c]) / Q;
}

// ---------------------------------------------------------------------------
extern "C" void kernel_launch(void* const* d_in, const int* in_sizes, int n_in,
                              void* d_out, int out_size, void* d_ws, size_t ws_size,
                              hipStream_t stream) {
    const float* A      = (const float*)d_in[0];
    const float* X      = (const float*)d_in[1];
    const float* W1     = (const float*)d_in[2];
    const float* b1     = (const float*)d_in[3];
    const float* W2     = (const float*)d_in[4];
    const float* b2     = (const float*)d_in[5];
    const float* lg0    = (const float*)d_in[6];
    const float* rdec   = (const float*)d_in[7];
    const float* ralpha = (const float*)d_in[8];
    float* out = (float*)d_out;

    char* w = (char*)d_ws;
    size_t off = 0;
    auto carve = [&](size_t bytes) -> char* {
        char* p = w + off;
        off += (bytes + 255) & ~(size_t)255;
        return p;
    };
    int*      rowcnt = (int*)carve(N_NODES * 4);
    int*      rowptr = (int*)carve((N_NODES + 16) * 4);
    int*      colIdx = (int*)carve(MAXE * 4);
    float*    y_e    = (float*)carve(MAXE * 4);
    unsigned* hist   = (unsigned*)carve(NBINS * 4);
    float*    D      = (float*)carve(N_NODES * 4);
    float*    isD    = (float*)carve(N_NODES * 4);
    float*    Fu     = (float*)carve((size_t)N_NODES * 64 * 4);
    float*    H1     = (float*)carve((size_t)N_NODES * H_DIM * 4);  // aliases tmpcols
    float*    F0     = (float*)carve((size_t)N_NODES * 64 * 4);
    float*    FcA    = (float*)carve((size_t)N_NODES * 64 * 4);
    float*    FcB    = (float*)carve((size_t)N_NODES * 64 * 4);
    float*    scal   = (float*)carve(256);
    int*      tmpcols = (int*)H1;   // dead before GEMMs run

    // CSR build: one pass over A + tiny scan/compact.
    k_degfill<<<dim3(N_NODES), dim3(256), 0, stream>>>(A, tmpcols, rowcnt, D, isD);
    k_scan<<<dim3(1), dim3(1024), 0, stream>>>(rowcnt, rowptr);
    k_compact<<<dim3(N_NODES), dim3(64), 0, stream>>>(tmpcols, rowcnt, rowptr, colIdx);

    // MLP: H1 = relu(X@W1 + b1); F0 = H1@W2 + b2
    k_gemm<H_DIM, IN_DIM, true><<<dim3(H_DIM / 64, N_NODES / 64), dim3(256), 0, stream>>>(X, W1, b1, H1);
    k_gemm<OUT_DIM, H_DIM, false><<<dim3(1, N_NODES / 64), dim3(256), 0, stream>>>(H1, W2, b2, F0);

    const float* fin = F0;
    float* fouts[4] = {FcA, FcB, FcA, out};
    for (int k = 0; k < 4; k++) {
        k_norm<<<dim3(1024), dim3(256), 0, stream>>>(fin, isD, Fu, hist);
        k_edge<<<dim3(1024), dim3(256), 0, stream>>>(Fu, rowptr, colIdx, y_e, hist);
        k_quant<<<dim3(1), dim3(1024), 0, stream>>>(hist, rowptr, lg0, rdec, ralpha, k, scal);
        k_prop<<<dim3(1024), dim3(256), 0, stream>>>(rowptr, colIdx, y_e, fin, F0, D, isD, scal, fouts[k]);
        fin = fouts[k];
    }
}

// Round 3
// 644.515 us; speedup vs baseline: 1.5697x; 1.5697x over previous
//
#include <hip/hip_runtime.h>
#include <math.h>

#define N_NODES 4096
#define IN_DIM  512
#define H_DIM   256
#define OUT_DIM 64
#define SCAD_Af 3.7f
#define EPSf    1e-8f
#define NBINS   16384
#define HBLOCKS 64
#define MAXE    524288
#define MAXD    256

// ---------------------------------------------------------------------------
// Fused: degree + column capture in ONE pass over A.
__global__ void k_degfill(const float* __restrict__ A, int* __restrict__ tmpcols,
                          int* __restrict__ rowcnt, float* __restrict__ D,
                          float* __restrict__ isD) {
    int i = blockIdx.x;
    __shared__ int cnt;
    if (threadIdx.x == 0) cnt = 0;
    __syncthreads();
    const float* row = A + (size_t)i * N_NODES;
    for (int j = threadIdx.x; j < N_NODES; j += blockDim.x) {
        if (row[j] != 0.0f) {
            int p = atomicAdd(&cnt, 1);   // LDS atomic, per-block only
            if (p < MAXD) tmpcols[i * MAXD + p] = j;
        }
    }
    __syncthreads();
    if (threadIdx.x == 0) {
        int t = cnt;
        rowcnt[i] = t;
        float d = (float)t + 1.0f;   // add_loops
        D[i] = d;
        isD[i] = 1.0f / sqrtf(d);
    }
}

// Exclusive scan of 4096 ints -> rowptr[0..4096]. Single block, 1024 threads.
__global__ void k_scan(const int* __restrict__ rowcnt, int* __restrict__ rowptr) {
    __shared__ int sh[1024];
    int t = threadIdx.x;
    int v0 = rowcnt[4 * t + 0], v1 = rowcnt[4 * t + 1];
    int v2 = rowcnt[4 * t + 2], v3 = rowcnt[4 * t + 3];
    int s = v0 + v1 + v2 + v3;
    sh[t] = s;
    __syncthreads();
    for (int off = 1; off < 1024; off <<= 1) {
        int x = 0;
        if (t >= off) x = sh[t - off];
        __syncthreads();
        sh[t] += x;
        __syncthreads();
    }
    int excl = sh[t] - s;
    rowptr[4 * t + 0] = excl;
    rowptr[4 * t + 1] = excl + v0;
    rowptr[4 * t + 2] = excl + v0 + v1;
    rowptr[4 * t + 3] = excl + v0 + v1 + v2;
    if (t == 1023) rowptr[N_NODES] = sh[1023];
}

// Compact tmpcols -> dense CSR colIdx.
__global__ void k_compact(const int* __restrict__ tmpcols, const int* __restrict__ rowcnt,
                          const int* __restrict__ rowptr, int* __restrict__ colIdx) {
    int i = blockIdx.x;
    int n = rowcnt[i], base = rowptr[i];
    for (int p = threadIdx.x; p < n; p += blockDim.x)
        colIdx[base + p] = tmpcols[i * MAXD + p];
}

// ---------------------------------------------------------------------------
// fp32 tiled GEMM: C[M,Nn] = act(Am[M,K] @ Bm[K,Nn] + bias). BM=BN=64, BK=16.
template <int Nn, int K, bool RELU>
__global__ void k_gemm(const float* __restrict__ Am, const float* __restrict__ Bm,
                       const float* __restrict__ bias, float* __restrict__ Cm) {
    __shared__ float As[16][68];
    __shared__ float Bs[16][64];
    int tx = threadIdx.x & 15, ty = threadIdx.x >> 4;
    int bm = blockIdx.y * 64, bn = blockIdx.x * 64;
    float acc[4][4] = {};
    for (int k0 = 0; k0 < K; k0 += 16) {
        {
            int r = threadIdx.x >> 2, kv = threadIdx.x & 3;
            float4 v = *(const float4*)(Am + (size_t)(bm + r) * K + k0 + kv * 4);
            As[kv * 4 + 0][r] = v.x;
            As[kv * 4 + 1][r] = v.y;
            As[kv * 4 + 2][r] = v.z;
            As[kv * 4 + 3][r] = v.w;
        }
        {
            int kk = threadIdx.x >> 4, nv = threadIdx.x & 15;
            *(float4*)&Bs[kk][nv * 4] =
                *(const float4*)(Bm + (size_t)(k0 + kk) * Nn + bn + nv * 4);
        }
        __syncthreads();
#pragma unroll
        for (int kk = 0; kk < 16; kk++) {
            float a[4], b[4];
#pragma unroll
            for (int u = 0; u < 4; u++) { a[u] = As[kk][ty * 4 + u]; b[u] = Bs[kk][tx * 4 + u]; }
#pragma unroll
            for (int u = 0; u < 4; u++)
#pragma unroll
                for (int v = 0; v < 4; v++) acc[u][v] += a[u] * b[v];
        }
        __syncthreads();
    }
#pragma unroll
    for (int u = 0; u < 4; u++) {
        int m = bm + ty * 4 + u;
#pragma unroll
        for (int v = 0; v < 4; v++) {
            int n = bn + tx * 4 + v;
            float x = acc[u][v] + bias[n];
            if (RELU) x = fmaxf(x, 0.0f);
            Cm[(size_t)m * Nn + n] = x;
        }
    }
}

// ---------------------------------------------------------------------------
// Row-normalize.
__global__ void k_norm(const float* __restrict__ Fc, const float* __restrict__ isD,
                       float* __restrict__ Fu) {
    int gid = blockIdx.x * blockDim.x + threadIdx.x;
    int i = gid >> 6, c = gid & 63;
    float fn = Fc[(size_t)i * 64 + c] * isD[i];
    float s = fn * fn;
    for (int off = 32; off; off >>= 1) s += __shfl_xor(s, off, 64);
    float nrm = sqrtf(s);
    Fu[(size_t)i * 64 + c] = fn / fmaxf(nrm, EPSf);
}

// Edge cosine distances. Wave per row; 16 edges in flight per wave:
// group g = lane>>2 owns edge base+g, sub-lane l = lane&3 owns channels
// l*16..l*16+15 (4 float4). Group reduce = 2 shfl_xor. NO atomics.
__global__ void k_edge(const float* __restrict__ Fu, const int* __restrict__ rowptr,
                       const int* __restrict__ colIdx, float* __restrict__ y_e) {
    int gid = blockIdx.x * blockDim.x + threadIdx.x;
    int i = gid >> 6;
    int lane = threadIdx.x & 63;
    int g = lane >> 2, l = lane & 3;
    int e0 = rowptr[i], e1 = rowptr[i + 1];
    const float4* Fu4 = (const float4*)Fu;
    float4 fi0 = Fu4[i * 16 + l * 4 + 0];
    float4 fi1 = Fu4[i * 16 + l * 4 + 1];
    float4 fi2 = Fu4[i * 16 + l * 4 + 2];
    float4 fi3 = Fu4[i * 16 + l * 4 + 3];
    for (int base = e0; base < e1; base += 16) {
        int e = base + g;
        bool act = e < e1;
        int j = act ? colIdx[e] : i;
        float4 a0 = Fu4[(size_t)j * 16 + l * 4 + 0];
        float4 a1 = Fu4[(size_t)j * 16 + l * 4 + 1];
        float4 a2 = Fu4[(size_t)j * 16 + l * 4 + 2];
        float4 a3 = Fu4[(size_t)j * 16 + l * 4 + 3];
        float s = fi0.x * a0.x + fi0.y * a0.y + fi0.z * a0.z + fi0.w * a0.w
                + fi1.x * a1.x + fi1.y * a1.y + fi1.z * a1.z + fi1.w * a1.w
                + fi2.x * a2.x + fi2.y * a2.y + fi2.z * a2.z + fi2.w * a2.w
                + fi3.x * a3.x + fi3.y * a3.y + fi3.z * a3.z + fi3.w * a3.w;
        s += __shfl_xor(s, 1, 64);
        s += __shfl_xor(s, 2, 64);
        if (act && l == 0) {
            float y = 1.0f - s;
            y_e[e] = fminf(fmaxf(y, 0.0f), 2.0f);
        }
    }
}

// LDS-privatized histogram. HBLOCKS blocks, each with a full 64KB LDS hist,
// flushed via plain coalesced stores to per-block partials. No global atomics.
__global__ void k_hist(const float* __restrict__ y_e, const int* __restrict__ rowptr,
                       unsigned int* __restrict__ partials) {
    __shared__ unsigned int hl[NBINS];
    for (int b = threadIdx.x; b < NBINS; b += blockDim.x) hl[b] = 0u;
    __syncthreads();
    int nE = rowptr[N_NODES];
    int stride = gridDim.x * blockDim.x;
    for (int e = blockIdx.x * blockDim.x + threadIdx.x; e < nE; e += stride) {
        int bin = (int)(y_e[e] * (NBINS * 0.5f));
        if (bin > NBINS - 1) bin = NBINS - 1;
        atomicAdd(&hl[bin], 1u);   // LDS atomic
    }
    __syncthreads();
    unsigned int* p = partials + (size_t)blockIdx.x * NBINS;
    for (int b = threadIdx.x; b < NBINS; b += blockDim.x) p[b] = hl[b];
}

// Sum partials + scan + rank-select the 0.75 nanquantile + lam_combined.
__global__ void k_quant(const unsigned int* __restrict__ partials,
                        const int* __restrict__ rowptr,
                        const float* __restrict__ lg0, const float* __restrict__ rdec,
                        const float* __restrict__ ralpha, int kiter,
                        float* __restrict__ scal) {
    __shared__ unsigned int psum[1024];
    __shared__ float vv[2];
    int t = threadIdx.x;
    unsigned int cnt[16];
#pragma unroll
    for (int q = 0; q < 16; q++) cnt[q] = 0u;
    for (int blk = 0; blk < HBLOCKS; blk++) {
        const uint4* p4 = (const uint4*)(partials + (size_t)blk * NBINS);
#pragma unroll
        for (int q = 0; q < 4; q++) {
            uint4 v = p4[t * 4 + q];
            cnt[q * 4 + 0] += v.x;
            cnt[q * 4 + 1] += v.y;
            cnt[q * 4 + 2] += v.z;
            cnt[q * 4 + 3] += v.w;
        }
    }
    unsigned int s = 0;
#pragma unroll
    for (int q = 0; q < 16; q++) s += cnt[q];
    psum[t] = s;
    __syncthreads();
    for (int off = 1; off < 1024; off <<= 1) {
        unsigned int x = 0;
        if (t >= off) x = psum[t - off];
        __syncthreads();
        psum[t] += x;
        __syncthreads();
    }
    int nE = rowptr[N_NODES];
    double h = 0.75 * (double)(nE - 1);
    long long i0 = (long long)h;
    float frac = (float)(h - (double)i0);
    unsigned int r0 = (unsigned int)i0, r1 = (unsigned int)(i0 + 1);
    unsigned int cum = (t == 0) ? 0u : psum[t - 1];
#pragma unroll
    for (int b = 0; b < 16; b++) {
        unsigned int cn = cnt[b];
        unsigned int lo = cum;
        cum += cn;
        if (cn) {
            float v = ((float)(t * 16 + b) + 0.5f) * (2.0f / (float)NBINS);
            if (lo <= r0 && r0 < cum) vv[0] = v;
            if (lo <= r1 && r1 < cum) vv[1] = v;
        }
    }
    __syncthreads();
    if (t == 0) {
        float gd = vv[0] + frac * (vv[1] - vv[0]);
        gd = fmaxf(gd, EPSf);
        float alpha = 1.0f / (1.0f + expf(-ralpha[0]));
        float g0 = expf(lg0[0]);
        float r = 1.0f / (1.0f + expf(-rdec[0]));
        float gp = g0;
        for (int q = 0; q < kiter; q++) gp *= r;
        scal[0] = alpha * (gp / SCAD_Af) + (1.0f - alpha) * (gd / SCAD_Af);
    }
}

__device__ __forceinline__ float scad_w(float y, float lamc) {
    if (y <= lamc) return 1.0f;
    if (y <= SCAD_Af * lamc)
        return (SCAD_Af * lamc - y) / ((SCAD_Af - 1.0f) * fmaxf(y, EPSf));
    return 0.0f;
}

// Sparse propagation, wave-per-row (lane = channel), 4 Fc-row loads in flight.
__global__ void k_prop(const int* __restrict__ rowptr, const int* __restrict__ colIdx,
                       const float* __restrict__ y_e, const float* __restrict__ Fc,
                       const float* __restrict__ F0, const float* __restrict__ D,
                       const float* __restrict__ isD, const float* __restrict__ scal,
                       float* __restrict__ Fout) {
    int gid = blockIdx.x * blockDim.x + threadIdx.x;
    int i = gid >> 6, c = gid & 63;
    float lamc = scal[0];
    const float lam = (float)(1.0 / 0.9 - 1.0);
    int e0 = rowptr[i], e1 = rowptr[i + 1];
    float acc = 0.0f, wsum = 0.0f;
    for (int base = e0; base < e1; base += 64) {
        int m = e1 - base; if (m > 64) m = 64;
        int   jl = (c < m) ? colIdx[base + c] : 0;
        float yl = (c < m) ? y_e[base + c] : 9.0f;
        float il = (c < m) ? isD[jl] : 0.0f;
        int t = 0;
        for (; t + 4 <= m; t += 4) {
            int j0 = __shfl(jl, t, 64),     j1 = __shfl(jl, t + 1, 64);
            int j2 = __shfl(jl, t + 2, 64), j3 = __shfl(jl, t + 3, 64);
            float f0 = Fc[(size_t)j0 * 64 + c], f1 = Fc[(size_t)j1 * 64 + c];
            float f2 = Fc[(size_t)j2 * 64 + c], f3 = Fc[(size_t)j3 * 64 + c];
            float w0 = scad_w(__shfl(yl, t, 64),     lamc) * __shfl(il, t, 64);
            float w1 = scad_w(__shfl(yl, t + 1, 64), lamc) * __shfl(il, t + 1, 64);
            float w2 = scad_w(__shfl(yl, t + 2, 64), lamc) * __shfl(il, t + 2, 64);
            float w3 = scad_w(__shfl(yl, t + 3, 64), lamc) * __shfl(il, t + 3, 64);
            // wsum needs raw w (not *isD[j]); recompute cheaply:
            wsum += scad_w(__shfl(yl, t, 64), lamc) + scad_w(__shfl(yl, t + 1, 64), lamc)
                  + scad_w(__shfl(yl, t + 2, 64), lamc) + scad_w(__shfl(yl, t + 3, 64), lamc);
            acc += w0 * f0 + w1 * f1 + w2 * f2 + w3 * f3;
        }
        for (; t < m; t++) {
            int   j = __shfl(jl, t, 64);
            float y = __shfl(yl, t, 64);
            float w = scad_w(y, lamc);
            wsum += w;
            acc += w * __shfl(il, t, 64) * Fc[(size_t)j * 64 + c];
        }
    }
    float Q = wsum / D[i] + lam;
    Fout[(size_t)i * 64 + c] = (isD[i] * acc + lam * F0[(size_t)i * 64 + c]) / Q;
}

// ---------------------------------------------------------------------------
extern "C" void kernel_launch(void* const* d_in, const int* in_sizes, int n_in,
                              void* d_out, int out_size, void* d_ws, size_t ws_size,
                              hipStream_t stream) {
    const float* A      = (const float*)d_in[0];
    const float* X      = (const float*)d_in[1];
    const float* W1     = (const float*)d_in[2];
    const float* b1     = (const float*)d_in[3];
    const float* W2     = (const float*)d_in[4];
    const float* b2     = (const float*)d_in[5];
    const float* lg0    = (const float*)d_in[6];
    const float* rdec   = (const float*)d_in[7];
    const float* ralpha = (const float*)d_in[8];
    float* out = (float*)d_out;

    char* w = (char*)d_ws;
    size_t off = 0;
    auto carve = [&](size_t bytes) -> char* {
        char* p = w + off;
        off += (bytes + 255) & ~(size_t)255;
        return p;
    };
    int*      rowcnt = (int*)carve(N_NODES * 4);
    int*      rowptr = (int*)carve((N_NODES + 16) * 4);
    int*      colIdx = (int*)carve(MAXE * 4);
    float*    y_e    = (float*)carve(MAXE * 4);
    float*    D      = (float*)carve(N_NODES * 4);
    float*    isD    = (float*)carve(N_NODES * 4);
    float*    Fu     = (float*)carve((size_t)N_NODES * 64 * 4);
    float*    H1     = (float*)carve((size_t)N_NODES * H_DIM * 4);  // 4 MB, multi-use
    float*    F0     = (float*)carve((size_t)N_NODES * 64 * 4);
    float*    FcA    = (float*)carve((size_t)N_NODES * 64 * 4);
    float*    FcB    = (float*)carve((size_t)N_NODES * 64 * 4);
    float*    scal   = (float*)carve(256);
    int*      tmpcols  = (int*)H1;       // dead before GEMMs
    unsigned* partials = (unsigned*)H1;  // HBLOCKS*NBINS*4 = 4 MB; dead after GEMMs

    // CSR build: one pass over A + tiny scan/compact.
    k_degfill<<<dim3(N_NODES), dim3(256), 0, stream>>>(A, tmpcols, rowcnt, D, isD);
    k_scan<<<dim3(1), dim3(1024), 0, stream>>>(rowcnt, rowptr);
    k_compact<<<dim3(N_NODES), dim3(64), 0, stream>>>(tmpcols, rowcnt, rowptr, colIdx);

    // MLP: H1 = relu(X@W1 + b1); F0 = H1@W2 + b2
    k_gemm<H_DIM, IN_DIM, true><<<dim3(H_DIM / 64, N_NODES / 64), dim3(256), 0, stream>>>(X, W1, b1, H1);
    k_gemm<OUT_DIM, H_DIM, false><<<dim3(1, N_NODES / 64), dim3(256), 0, stream>>>(H1, W2, b2, F0);

    const float* fin = F0;
    float* fouts[4] = {FcA, FcB, FcA, out};
    for (int k = 0; k < 4; k++) {
        k_norm<<<dim3(1024), dim3(256), 0, stream>>>(fin, isD, Fu);
        k_edge<<<dim3(1024), dim3(256), 0, stream>>>(Fu, rowptr, colIdx, y_e);
        k_hist<<<dim3(HBLOCKS), dim3(256), 0, stream>>>(y_e, rowptr, partials);
        k_quant<<<dim3(1), dim3(1024), 0, stream>>>(partials, rowptr, lg0, rdec, ralpha, k, scal);
        k_prop<<<dim3(1024), dim3(256), 0, stream>>>(rowptr, colIdx, y_e, fin, F0, D, isD, scal, fouts[k]);
        fin = fouts[k];
    }
}

// Round 4
// 414.267 us; speedup vs baseline: 2.4421x; 1.5558x over previous
//
#include <hip/hip_runtime.h>
#include <math.h>

#define N_NODES 4096
#define IN_DIM  512
#define H_DIM   256
#define OUT_DIM 64
#define SCAD_Af 3.7f
#define EPSf    1e-8f
#define NBINS   16384
#define HBLOCKS 16
#define MAXE    524288
#define MAXD    256

// ---------------------------------------------------------------------------
// Fused: degree + column capture in ONE pass over A.
__global__ void k_degfill(const float* __restrict__ A, int* __restrict__ tmpcols,
                          int* __restrict__ rowcnt, float* __restrict__ D,
                          float* __restrict__ isD) {
    int i = blockIdx.x;
    __shared__ int cnt;
    if (threadIdx.x == 0) cnt = 0;
    __syncthreads();
    const float* row = A + (size_t)i * N_NODES;
    for (int j = threadIdx.x; j < N_NODES; j += blockDim.x) {
        if (row[j] != 0.0f) {
            int p = atomicAdd(&cnt, 1);   // LDS atomic, per-block only
            if (p < MAXD) tmpcols[i * MAXD + p] = j;
        }
    }
    __syncthreads();
    if (threadIdx.x == 0) {
        int t = cnt;
        rowcnt[i] = t;
        float d = (float)t + 1.0f;   // add_loops
        D[i] = d;
        isD[i] = 1.0f / sqrtf(d);
    }
}

// Exclusive scan of 4096 ints -> rowptr[0..4096]. Single block, 1024 threads.
__global__ void k_scan(const int* __restrict__ rowcnt, int* __restrict__ rowptr) {
    __shared__ int sh[1024];
    int t = threadIdx.x;
    int v0 = rowcnt[4 * t + 0], v1 = rowcnt[4 * t + 1];
    int v2 = rowcnt[4 * t + 2], v3 = rowcnt[4 * t + 3];
    int s = v0 + v1 + v2 + v3;
    sh[t] = s;
    __syncthreads();
    for (int off = 1; off < 1024; off <<= 1) {
        int x = 0;
        if (t >= off) x = sh[t - off];
        __syncthreads();
        sh[t] += x;
        __syncthreads();
    }
    int excl = sh[t] - s;
    rowptr[4 * t + 0] = excl;
    rowptr[4 * t + 1] = excl + v0;
    rowptr[4 * t + 2] = excl + v0 + v1;
    rowptr[4 * t + 3] = excl + v0 + v1 + v2;
    if (t == 1023) rowptr[N_NODES] = sh[1023];
}

// Compact tmpcols -> dense CSR colIdx.
__global__ void k_compact(const int* __restrict__ tmpcols, const int* __restrict__ rowcnt,
                          const int* __restrict__ rowptr, int* __restrict__ colIdx) {
    int i = blockIdx.x;
    int n = rowcnt[i], base = rowptr[i];
    for (int p = threadIdx.x; p < n; p += blockDim.x)
        colIdx[base + p] = tmpcols[i * MAXD + p];
}

// ---------------------------------------------------------------------------
// fp32 tiled GEMM: C[M,Nn] = act(Am[M,K] @ Bm[K,Nn] + bias). BM=BN=64, BK=16.
template <int Nn, int K, bool RELU>
__global__ void k_gemm(const float* __restrict__ Am, const float* __restrict__ Bm,
                       const float* __restrict__ bias, float* __restrict__ Cm) {
    __shared__ float As[16][68];
    __shared__ float Bs[16][64];
    int tx = threadIdx.x & 15, ty = threadIdx.x >> 4;
    int bm = blockIdx.y * 64, bn = blockIdx.x * 64;
    float acc[4][4] = {};
    for (int k0 = 0; k0 < K; k0 += 16) {
        {
            int r = threadIdx.x >> 2, kv = threadIdx.x & 3;
            float4 v = *(const float4*)(Am + (size_t)(bm + r) * K + k0 + kv * 4);
            As[kv * 4 + 0][r] = v.x;
            As[kv * 4 + 1][r] = v.y;
            As[kv * 4 + 2][r] = v.z;
            As[kv * 4 + 3][r] = v.w;
        }
        {
            int kk = threadIdx.x >> 4, nv = threadIdx.x & 15;
            *(float4*)&Bs[kk][nv * 4] =
                *(const float4*)(Bm + (size_t)(k0 + kk) * Nn + bn + nv * 4);
        }
        __syncthreads();
#pragma unroll
        for (int kk = 0; kk < 16; kk++) {
            float a[4], b[4];
#pragma unroll
            for (int u = 0; u < 4; u++) { a[u] = As[kk][ty * 4 + u]; b[u] = Bs[kk][tx * 4 + u]; }
#pragma unroll
            for (int u = 0; u < 4; u++)
#pragma unroll
                for (int v = 0; v < 4; v++) acc[u][v] += a[u] * b[v];
        }
        __syncthreads();
    }
#pragma unroll
    for (int u = 0; u < 4; u++) {
        int m = bm + ty * 4 + u;
#pragma unroll
        for (int v = 0; v < 4; v++) {
            int n = bn + tx * 4 + v;
            float x = acc[u][v] + bias[n];
            if (RELU) x = fmaxf(x, 0.0f);
            Cm[(size_t)m * Nn + n] = x;
        }
    }
}

// ---------------------------------------------------------------------------
// Row-normalize + zero the shared histogram (piggyback; ordered before k_hist).
__global__ void k_norm(const float* __restrict__ Fc, const float* __restrict__ isD,
                       float* __restrict__ Fu, unsigned int* __restrict__ hist) {
    int gid = blockIdx.x * blockDim.x + threadIdx.x;
    if (gid < NBINS) hist[gid] = 0u;
    int i = gid >> 6, c = gid & 63;
    float fn = Fc[(size_t)i * 64 + c] * isD[i];
    float s = fn * fn;
    for (int off = 32; off; off >>= 1) s += __shfl_xor(s, off, 64);
    float nrm = sqrtf(s);
    Fu[(size_t)i * 64 + c] = fn / fmaxf(nrm, EPSf);
}

// Edge cosine distances. Wave per row; 16 edges in flight per wave:
// group g = lane>>2 owns edge base+g, sub-lane l = lane&3 owns channels
// l*16..l*16+15 (4 float4). Group reduce = 2 shfl_xor. NO atomics.
__global__ void k_edge(const float* __restrict__ Fu, const int* __restrict__ rowptr,
                       const int* __restrict__ colIdx, float* __restrict__ y_e) {
    int gid = blockIdx.x * blockDim.x + threadIdx.x;
    int i = gid >> 6;
    int lane = threadIdx.x & 63;
    int g = lane >> 2, l = lane & 3;
    int e0 = rowptr[i], e1 = rowptr[i + 1];
    const float4* Fu4 = (const float4*)Fu;
    float4 fi0 = Fu4[i * 16 + l * 4 + 0];
    float4 fi1 = Fu4[i * 16 + l * 4 + 1];
    float4 fi2 = Fu4[i * 16 + l * 4 + 2];
    float4 fi3 = Fu4[i * 16 + l * 4 + 3];
    for (int base = e0; base < e1; base += 16) {
        int e = base + g;
        bool act = e < e1;
        int j = act ? colIdx[e] : i;
        float4 a0 = Fu4[(size_t)j * 16 + l * 4 + 0];
        float4 a1 = Fu4[(size_t)j * 16 + l * 4 + 1];
        float4 a2 = Fu4[(size_t)j * 16 + l * 4 + 2];
        float4 a3 = Fu4[(size_t)j * 16 + l * 4 + 3];
        float s = fi0.x * a0.x + fi0.y * a0.y + fi0.z * a0.z + fi0.w * a0.w
                + fi1.x * a1.x + fi1.y * a1.y + fi1.z * a1.z + fi1.w * a1.w
                + fi2.x * a2.x + fi2.y * a2.y + fi2.z * a2.z + fi2.w * a2.w
                + fi3.x * a3.x + fi3.y * a3.y + fi3.z * a3.z + fi3.w * a3.w;
        s += __shfl_xor(s, 1, 64);
        s += __shfl_xor(s, 2, 64);
        if (act && l == 0) {
            float y = 1.0f - s;
            y_e[e] = fminf(fmaxf(y, 0.0f), 2.0f);
        }
    }
}

// LDS-privatized histogram; flush NONZERO bins with device atomicAdd into one
// global hist (<= HBLOCKS adds per bin; spread addresses -> L2 throughput).
__global__ void k_hist(const float* __restrict__ y_e, const int* __restrict__ rowptr,
                       unsigned int* __restrict__ hist) {
    __shared__ unsigned int hl[NBINS];
    for (int b = threadIdx.x; b < NBINS; b += blockDim.x) hl[b] = 0u;
    __syncthreads();
    int nE = rowptr[N_NODES];
    int stride = gridDim.x * blockDim.x;
    for (int e = blockIdx.x * blockDim.x + threadIdx.x; e < nE; e += stride) {
        int bin = (int)(y_e[e] * (NBINS * 0.5f));
        if (bin > NBINS - 1) bin = NBINS - 1;
        atomicAdd(&hl[bin], 1u);   // LDS atomic
    }
    __syncthreads();
    for (int b = threadIdx.x; b < NBINS; b += blockDim.x) {
        unsigned int v = hl[b];
        if (v) atomicAdd(&hist[b], v);
    }
}

// Scan the 64KB hist + rank-select the 0.75 nanquantile + lam_combined scalar.
__global__ void k_quant(const unsigned int* __restrict__ hist,
                        const int* __restrict__ rowptr,
                        const float* __restrict__ lg0, const float* __restrict__ rdec,
                        const float* __restrict__ ralpha, int kiter,
                        float* __restrict__ scal) {
    __shared__ unsigned int psum[1024];
    __shared__ float vv[2];
    int t = threadIdx.x;
    unsigned int cnt[16];
    const uint4* h4 = (const uint4*)hist;
#pragma unroll
    for (int q = 0; q < 4; q++) {
        uint4 v = h4[t * 4 + q];
        cnt[q * 4 + 0] = v.x;
        cnt[q * 4 + 1] = v.y;
        cnt[q * 4 + 2] = v.z;
        cnt[q * 4 + 3] = v.w;
    }
    unsigned int s = 0;
#pragma unroll
    for (int q = 0; q < 16; q++) s += cnt[q];
    psum[t] = s;
    __syncthreads();
    for (int off = 1; off < 1024; off <<= 1) {
        unsigned int x = 0;
        if (t >= off) x = psum[t - off];
        __syncthreads();
        psum[t] += x;
        __syncthreads();
    }
    int nE = rowptr[N_NODES];
    double h = 0.75 * (double)(nE - 1);
    long long i0 = (long long)h;
    float frac = (float)(h - (double)i0);
    unsigned int r0 = (unsigned int)i0, r1 = (unsigned int)(i0 + 1);
    unsigned int cum = (t == 0) ? 0u : psum[t - 1];
#pragma unroll
    for (int b = 0; b < 16; b++) {
        unsigned int cn = cnt[b];
        unsigned int lo = cum;
        cum += cn;
        if (cn) {
            float v = ((float)(t * 16 + b) + 0.5f) * (2.0f / (float)NBINS);
            if (lo <= r0 && r0 < cum) vv[0] = v;
            if (lo <= r1 && r1 < cum) vv[1] = v;
        }
    }
    __syncthreads();
    if (t == 0) {
        float gd = vv[0] + frac * (vv[1] - vv[0]);
        gd = fmaxf(gd, EPSf);
        float alpha = 1.0f / (1.0f + expf(-ralpha[0]));
        float g0 = expf(lg0[0]);
        float r = 1.0f / (1.0f + expf(-rdec[0]));
        float gp = g0;
        for (int q = 0; q < kiter; q++) gp *= r;
        scal[0] = alpha * (gp / SCAD_Af) + (1.0f - alpha) * (gd / SCAD_Af);
    }
}

__device__ __forceinline__ float scad_w(float y, float lamc) {
    if (y <= lamc) return 1.0f;
    if (y <= SCAD_Af * lamc)
        return (SCAD_Af * lamc - y) / ((SCAD_Af - 1.0f) * fmaxf(y, EPSf));
    return 0.0f;
}

// Sparse propagation, wave-per-row (lane = channel), 4 Fc-row loads in flight.
__global__ void k_prop(const int* __restrict__ rowptr, const int* __restrict__ colIdx,
                       const float* __restrict__ y_e, const float* __restrict__ Fc,
                       const float* __restrict__ F0, const float* __restrict__ D,
                       const float* __restrict__ isD, const float* __restrict__ scal,
                       float* __restrict__ Fout) {
    int gid = blockIdx.x * blockDim.x + threadIdx.x;
    int i = gid >> 6, c = gid & 63;
    float lamc = scal[0];
    const float lam = (float)(1.0 / 0.9 - 1.0);
    int e0 = rowptr[i], e1 = rowptr[i + 1];
    float acc = 0.0f, wsum = 0.0f;
    for (int base = e0; base < e1; base += 64) {
        int m = e1 - base; if (m > 64) m = 64;
        int   jl = (c < m) ? colIdx[base + c] : 0;
        float yl = (c < m) ? y_e[base + c] : 9.0f;
        float il = (c < m) ? isD[jl] : 0.0f;
        int t = 0;
        for (; t + 4 <= m; t += 4) {
            int j0 = __shfl(jl, t, 64),     j1 = __shfl(jl, t + 1, 64);
            int j2 = __shfl(jl, t + 2, 64), j3 = __shfl(jl, t + 3, 64);
            float f0 = Fc[(size_t)j0 * 64 + c], f1 = Fc[(size_t)j1 * 64 + c];
            float f2 = Fc[(size_t)j2 * 64 + c], f3 = Fc[(size_t)j3 * 64 + c];
            float s0 = scad_w(__shfl(yl, t, 64),     lamc);
            float s1 = scad_w(__shfl(yl, t + 1, 64), lamc);
            float s2 = scad_w(__shfl(yl, t + 2, 64), lamc);
            float s3 = scad_w(__shfl(yl, t + 3, 64), lamc);
            wsum += s0 + s1 + s2 + s3;
            acc += s0 * __shfl(il, t, 64) * f0 + s1 * __shfl(il, t + 1, 64) * f1
                 + s2 * __shfl(il, t + 2, 64) * f2 + s3 * __shfl(il, t + 3, 64) * f3;
        }
        for (; t < m; t++) {
            int   j = __shfl(jl, t, 64);
            float y = __shfl(yl, t, 64);
            float w = scad_w(y, lamc);
            wsum += w;
            acc += w * __shfl(il, t, 64) * Fc[(size_t)j * 64 + c];
        }
    }
    float Q = wsum / D[i] + lam;
    Fout[(size_t)i * 64 + c] = (isD[i] * acc + lam * F0[(size_t)i * 64 + c]) / Q;
}

// ---------------------------------------------------------------------------
extern "C" void kernel_launch(void* const* d_in, const int* in_sizes, int n_in,
                              void* d_out, int out_size, void* d_ws, size_t ws_size,
                              hipStream_t stream) {
    const float* A      = (const float*)d_in[0];
    const float* X      = (const float*)d_in[1];
    const float* W1     = (const float*)d_in[2];
    const float* b1     = (const float*)d_in[3];
    const float* W2     = (const float*)d_in[4];
    const float* b2     = (const float*)d_in[5];
    const float* lg0    = (const float*)d_in[6];
    const float* rdec   = (const float*)d_in[7];
    const float* ralpha = (const float*)d_in[8];
    float* out = (float*)d_out;

    char* w = (char*)d_ws;
    size_t off = 0;
    auto carve = [&](size_t bytes) -> char* {
        char* p = w + off;
        off += (bytes + 255) & ~(size_t)255;
        return p;
    };
    int*      rowcnt = (int*)carve(N_NODES * 4);
    int*      rowptr = (int*)carve((N_NODES + 16) * 4);
    int*      colIdx = (int*)carve(MAXE * 4);
    float*    y_e    = (float*)carve(MAXE * 4);
    unsigned* hist   = (unsigned*)carve(NBINS * 4);
    float*    D      = (float*)carve(N_NODES * 4);
    float*    isD    = (float*)carve(N_NODES * 4);
    float*    Fu     = (float*)carve((size_t)N_NODES * 64 * 4);
    float*    H1     = (float*)carve((size_t)N_NODES * H_DIM * 4);  // 4 MB, multi-use
    float*    F0     = (float*)carve((size_t)N_NODES * 64 * 4);
    float*    FcA    = (float*)carve((size_t)N_NODES * 64 * 4);
    float*    FcB    = (float*)carve((size_t)N_NODES * 64 * 4);
    float*    scal   = (float*)carve(256);
    int*      tmpcols = (int*)H1;   // dead before GEMMs

    // CSR build: one pass over A + tiny scan/compact.
    k_degfill<<<dim3(N_NODES), dim3(256), 0, stream>>>(A, tmpcols, rowcnt, D, isD);
    k_scan<<<dim3(1), dim3(1024), 0, stream>>>(rowcnt, rowptr);
    k_compact<<<dim3(N_NODES), dim3(64), 0, stream>>>(tmpcols, rowcnt, rowptr, colIdx);

    // MLP: H1 = relu(X@W1 + b1); F0 = H1@W2 + b2
    k_gemm<H_DIM, IN_DIM, true><<<dim3(H_DIM / 64, N_NODES / 64), dim3(256), 0, stream>>>(X, W1, b1, H1);
    k_gemm<OUT_DIM, H_DIM, false><<<dim3(1, N_NODES / 64), dim3(256), 0, stream>>>(H1, W2, b2, F0);

    const float* fin = F0;
    float* fouts[4] = {FcA, FcB, FcA, out};
    for (int k = 0; k < 4; k++) {
        k_norm<<<dim3(1024), dim3(256), 0, stream>>>(fin, isD, Fu, hist);
        k_edge<<<dim3(1024), dim3(256), 0, stream>>>(Fu, rowptr, colIdx, y_e);
        k_hist<<<dim3(HBLOCKS), dim3(256), 0, stream>>>(y_e, rowptr, hist);
        k_quant<<<dim3(1), dim3(1024), 0, stream>>>(hist, rowptr, lg0, rdec, ralpha, k, scal);
        k_prop<<<dim3(1024), dim3(256), 0, stream>>>(rowptr, colIdx, y_e, fin, F0, D, isD, scal, fouts[k]);
        fin = fouts[k];
    }
}

// Round 5
// 384.325 us; speedup vs baseline: 2.6323x; 1.0779x over previous
//
#include <hip/hip_runtime.h>
#include <math.h>

#define N_NODES 4096
#define IN_DIM  512
#define H_DIM   256
#define OUT_DIM 64
#define SCAD_Af 3.7f
#define EPSf    1e-8f
#define NBINS   8192      // 32 KB LDS hist; bin width 2.44e-4 (quantile err << tol)
#define MAXE    524288
#define MAXD    256
#define KSPLIT  4

// ---------------------------------------------------------------------------
// Fused: degree + column capture in ONE pass over A.
__global__ void k_degfill(const float* __restrict__ A, int* __restrict__ tmpcols,
                          int* __restrict__ rowcnt, float* __restrict__ D,
                          float* __restrict__ isD) {
    int i = blockIdx.x;
    __shared__ int cnt;
    if (threadIdx.x == 0) cnt = 0;
    __syncthreads();
    const float* row = A + (size_t)i * N_NODES;
    for (int j = threadIdx.x; j < N_NODES; j += blockDim.x) {
        if (row[j] != 0.0f) {
            int p = atomicAdd(&cnt, 1);   // LDS atomic, per-block only
            if (p < MAXD) tmpcols[i * MAXD + p] = j;
        }
    }
    __syncthreads();
    if (threadIdx.x == 0) {
        int t = cnt;
        rowcnt[i] = t;
        float d = (float)t + 1.0f;   // add_loops
        D[i] = d;
        isD[i] = 1.0f / sqrtf(d);
    }
}

// Exclusive scan of 4096 ints -> rowptr[0..4096]. Single block, 1024 threads.
__global__ void k_scan(const int* __restrict__ rowcnt, int* __restrict__ rowptr) {
    __shared__ int sh[1024];
    int t = threadIdx.x;
    int v0 = rowcnt[4 * t + 0], v1 = rowcnt[4 * t + 1];
    int v2 = rowcnt[4 * t + 2], v3 = rowcnt[4 * t + 3];
    int s = v0 + v1 + v2 + v3;
    sh[t] = s;
    __syncthreads();
    for (int off = 1; off < 1024; off <<= 1) {
        int x = 0;
        if (t >= off) x = sh[t - off];
        __syncthreads();
        sh[t] += x;
        __syncthreads();
    }
    int excl = sh[t] - s;
    rowptr[4 * t + 0] = excl;
    rowptr[4 * t + 1] = excl + v0;
    rowptr[4 * t + 2] = excl + v0 + v1;
    rowptr[4 * t + 3] = excl + v0 + v1 + v2;
    if (t == 1023) rowptr[N_NODES] = sh[1023];
}

// Compact tmpcols -> dense CSR colIdx.
__global__ void k_compact(const int* __restrict__ tmpcols, const int* __restrict__ rowcnt,
                          const int* __restrict__ rowptr, int* __restrict__ colIdx) {
    int i = blockIdx.x;
    int n = rowcnt[i], base = rowptr[i];
    for (int p = threadIdx.x; p < n; p += blockDim.x)
        colIdx[base + p] = tmpcols[i * MAXD + p];
}

// ---------------------------------------------------------------------------
// GEMM1 with K-split: each block does a 64x64 tile over K/KSPLIT=128 into
// part[ks]. Grid (4, 64, KSPLIT) = 1024 blocks -> 4 waves/SIMD (was 1).
__global__ void k_gemm1_part(const float* __restrict__ X, const float* __restrict__ W1,
                             float* __restrict__ part) {
    const int K = IN_DIM, Nn = H_DIM;
    __shared__ float As[16][68];
    __shared__ float Bs[16][64];
    int tx = threadIdx.x & 15, ty = threadIdx.x >> 4;
    int bm = blockIdx.y * 64, bn = blockIdx.x * 64;
    int kbeg = blockIdx.z * (K / KSPLIT), kend = kbeg + K / KSPLIT;
    float acc[4][4] = {};
    for (int k0 = kbeg; k0 < kend; k0 += 16) {
        {
            int r = threadIdx.x >> 2, kv = threadIdx.x & 3;
            float4 v = *(const float4*)(X + (size_t)(bm + r) * K + k0 + kv * 4);
            As[kv * 4 + 0][r] = v.x;
            As[kv * 4 + 1][r] = v.y;
            As[kv * 4 + 2][r] = v.z;
            As[kv * 4 + 3][r] = v.w;
        }
        {
            int kk = threadIdx.x >> 4, nv = threadIdx.x & 15;
            *(float4*)&Bs[kk][nv * 4] =
                *(const float4*)(W1 + (size_t)(k0 + kk) * Nn + bn + nv * 4);
        }
        __syncthreads();
#pragma unroll
        for (int kk = 0; kk < 16; kk++) {
            float a[4], b[4];
#pragma unroll
            for (int u = 0; u < 4; u++) { a[u] = As[kk][ty * 4 + u]; b[u] = Bs[kk][tx * 4 + u]; }
#pragma unroll
            for (int u = 0; u < 4; u++)
#pragma unroll
                for (int v = 0; v < 4; v++) acc[u][v] += a[u] * b[v];
        }
        __syncthreads();
    }
    float* Cm = part + (size_t)blockIdx.z * N_NODES * H_DIM;
#pragma unroll
    for (int u = 0; u < 4; u++) {
        int m = bm + ty * 4 + u;
#pragma unroll
        for (int v = 0; v < 4; v++)
            Cm[(size_t)m * Nn + bn + tx * 4 + v] = acc[u][v];
    }
}

// Sum KSPLIT partials + bias + relu -> H1. float4 per thread.
__global__ void k_fuse1(const float* __restrict__ part, const float* __restrict__ bias,
                        float* __restrict__ H1) {
    int idx = blockIdx.x * blockDim.x + threadIdx.x;          // float4 index
    const size_t tot = (size_t)N_NODES * H_DIM / 4;           // 262144
    const float4* p = (const float4*)part;
    float4 a = p[idx], b = p[tot + idx], c = p[2 * tot + idx], d = p[3 * tot + idx];
    float4 bb = ((const float4*)bias)[idx & (H_DIM / 4 - 1)];
    float4 r;
    r.x = fmaxf(a.x + b.x + c.x + d.x + bb.x, 0.0f);
    r.y = fmaxf(a.y + b.y + c.y + d.y + bb.y, 0.0f);
    r.z = fmaxf(a.z + b.z + c.z + d.z + bb.z, 0.0f);
    r.w = fmaxf(a.w + b.w + c.w + d.w + bb.w, 0.0f);
    ((float4*)H1)[idx] = r;
}

// GEMM2 (small): C[M,64] = H1[M,256] @ W2[256,64] + b2. BM=BN=64, BK=16.
__global__ void k_gemm2(const float* __restrict__ Am, const float* __restrict__ Bm,
                        const float* __restrict__ bias, float* __restrict__ Cm) {
    const int Nn = OUT_DIM, K = H_DIM;
    __shared__ float As[16][68];
    __shared__ float Bs[16][64];
    int tx = threadIdx.x & 15, ty = threadIdx.x >> 4;
    int bm = blockIdx.y * 64, bn = 0;
    float acc[4][4] = {};
    for (int k0 = 0; k0 < K; k0 += 16) {
        {
            int r = threadIdx.x >> 2, kv = threadIdx.x & 3;
            float4 v = *(const float4*)(Am + (size_t)(bm + r) * K + k0 + kv * 4);
            As[kv * 4 + 0][r] = v.x;
            As[kv * 4 + 1][r] = v.y;
            As[kv * 4 + 2][r] = v.z;
            As[kv * 4 + 3][r] = v.w;
        }
        {
            int kk = threadIdx.x >> 4, nv = threadIdx.x & 15;
            *(float4*)&Bs[kk][nv * 4] =
                *(const float4*)(Bm + (size_t)(k0 + kk) * Nn + bn + nv * 4);
        }
        __syncthreads();
#pragma unroll
        for (int kk = 0; kk < 16; kk++) {
            float a[4], b[4];
#pragma unroll
            for (int u = 0; u < 4; u++) { a[u] = As[kk][ty * 4 + u]; b[u] = Bs[kk][tx * 4 + u]; }
#pragma unroll
            for (int u = 0; u < 4; u++)
#pragma unroll
                for (int v = 0; v < 4; v++) acc[u][v] += a[u] * b[v];
        }
        __syncthreads();
    }
#pragma unroll
    for (int u = 0; u < 4; u++) {
        int m = bm + ty * 4 + u;
#pragma unroll
        for (int v = 0; v < 4; v++) {
            int n = bn + tx * 4 + v;
            Cm[(size_t)m * Nn + n] = acc[u][v] + bias[n];
        }
    }
}

// ---------------------------------------------------------------------------
// Row-normalize + zero the shared histogram (piggyback; ordered before edgehist).
__global__ void k_norm(const float* __restrict__ Fc, const float* __restrict__ isD,
                       float* __restrict__ Fu, unsigned int* __restrict__ hist) {
    int gid = blockIdx.x * blockDim.x + threadIdx.x;
    if (gid < NBINS) hist[gid] = 0u;
    int i = gid >> 6, c = gid & 63;
    float fn = Fc[(size_t)i * 64 + c] * isD[i];
    float s = fn * fn;
    for (int off = 32; off; off >>= 1) s += __shfl_xor(s, off, 64);
    float nrm = sqrtf(s);
    Fu[(size_t)i * 64 + c] = fn / fmaxf(nrm, EPSf);
}

// Edge cosine distances + LDS-privatized histogram, fused. Wave per row;
// 16 edges in flight (group g = lane>>2 owns edge, l = lane&3 owns 16 chans).
__global__ void k_edgehist(const float* __restrict__ Fu, const int* __restrict__ rowptr,
                           const int* __restrict__ colIdx, float* __restrict__ y_e,
                           unsigned int* __restrict__ hist) {
    __shared__ unsigned int hl[NBINS];
    for (int b = threadIdx.x; b < NBINS; b += blockDim.x) hl[b] = 0u;
    __syncthreads();
    int gid = blockIdx.x * blockDim.x + threadIdx.x;
    int i = gid >> 6;
    int lane = threadIdx.x & 63;
    int g = lane >> 2, l = lane & 3;
    int e0 = rowptr[i], e1 = rowptr[i + 1];
    const float4* Fu4 = (const float4*)Fu;
    float4 fi0 = Fu4[i * 16 + l * 4 + 0];
    float4 fi1 = Fu4[i * 16 + l * 4 + 1];
    float4 fi2 = Fu4[i * 16 + l * 4 + 2];
    float4 fi3 = Fu4[i * 16 + l * 4 + 3];
    for (int base = e0; base < e1; base += 16) {
        int e = base + g;
        bool act = e < e1;
        int j = act ? colIdx[e] : i;
        float4 a0 = Fu4[(size_t)j * 16 + l * 4 + 0];
        float4 a1 = Fu4[(size_t)j * 16 + l * 4 + 1];
        float4 a2 = Fu4[(size_t)j * 16 + l * 4 + 2];
        float4 a3 = Fu4[(size_t)j * 16 + l * 4 + 3];
        float s = fi0.x * a0.x + fi0.y * a0.y + fi0.z * a0.z + fi0.w * a0.w
                + fi1.x * a1.x + fi1.y * a1.y + fi1.z * a1.z + fi1.w * a1.w
                + fi2.x * a2.x + fi2.y * a2.y + fi2.z * a2.z + fi2.w * a2.w
                + fi3.x * a3.x + fi3.y * a3.y + fi3.z * a3.z + fi3.w * a3.w;
        s += __shfl_xor(s, 1, 64);
        s += __shfl_xor(s, 2, 64);
        if (act && l == 0) {
            float y = 1.0f - s;
            y = fminf(fmaxf(y, 0.0f), 2.0f);
            y_e[e] = y;
            int bin = (int)(y * (NBINS * 0.5f));
            if (bin > NBINS - 1) bin = NBINS - 1;
            atomicAdd(&hl[bin], 1u);   // LDS atomic
        }
    }
    __syncthreads();
    for (int b = threadIdx.x; b < NBINS; b += blockDim.x) {
        unsigned int v = hl[b];
        if (v) atomicAdd(&hist[b], v);   // sparse device-atomic flush
    }
}

__device__ __forceinline__ float scad_w(float y, float lamc) {
    if (y <= lamc) return 1.0f;
    if (y <= SCAD_Af * lamc)
        return (SCAD_Af * lamc - y) / ((SCAD_Af - 1.0f) * fmaxf(y, EPSf));
    return 0.0f;
}

// Quantile (redundant per-block scan of the 32KB hist) + sparse propagation.
__global__ void k_propq(const unsigned int* __restrict__ hist,
                        const int* __restrict__ rowptr, const int* __restrict__ colIdx,
                        const float* __restrict__ y_e, const float* __restrict__ Fc,
                        const float* __restrict__ F0, const float* __restrict__ D,
                        const float* __restrict__ isD,
                        const float* __restrict__ lg0, const float* __restrict__ rdec,
                        const float* __restrict__ ralpha, int kiter,
                        float* __restrict__ Fout) {
    __shared__ unsigned int psum[256];
    __shared__ float vv[2];
    __shared__ float sh_scal;
    int t = threadIdx.x;
    {   // ---- quantile phase: 8192 bins, 32/thread ----
        unsigned int cnt[32];
        const uint4* h4 = (const uint4*)hist;
        unsigned int s = 0;
#pragma unroll
        for (int q = 0; q < 8; q++) {
            uint4 v = h4[t * 8 + q];
            cnt[q * 4 + 0] = v.x; cnt[q * 4 + 1] = v.y;
            cnt[q * 4 + 2] = v.z; cnt[q * 4 + 3] = v.w;
            s += v.x + v.y + v.z + v.w;
        }
        psum[t] = s;
        __syncthreads();
        for (int off = 1; off < 256; off <<= 1) {
            unsigned int x = 0;
            if (t >= off) x = psum[t - off];
            __syncthreads();
            psum[t] += x;
            __syncthreads();
        }
        int nE = rowptr[N_NODES];
        double h = 0.75 * (double)(nE - 1);
        long long i0 = (long long)h;
        float frac = (float)(h - (double)i0);
        unsigned int r0 = (unsigned int)i0, r1 = (unsigned int)(i0 + 1);
        unsigned int cum = (t == 0) ? 0u : psum[t - 1];
#pragma unroll
        for (int b = 0; b < 32; b++) {
            unsigned int cn = cnt[b];
            unsigned int lo = cum;
            cum += cn;
            if (cn) {
                float v = ((float)(t * 32 + b) + 0.5f) * (2.0f / (float)NBINS);
                if (lo <= r0 && r0 < cum) vv[0] = v;
                if (lo <= r1 && r1 < cum) vv[1] = v;
            }
        }
        __syncthreads();
        if (t == 0) {
            float gd = vv[0] + frac * (vv[1] - vv[0]);
            gd = fmaxf(gd, EPSf);
            float alpha = 1.0f / (1.0f + expf(-ralpha[0]));
            float g0 = expf(lg0[0]);
            float r = 1.0f / (1.0f + expf(-rdec[0]));
            float gp = g0;
            for (int q = 0; q < kiter; q++) gp *= r;
            sh_scal = alpha * (gp / SCAD_Af) + (1.0f - alpha) * (gd / SCAD_Af);
        }
        __syncthreads();
    }
    float lamc = sh_scal;
    const float lam = (float)(1.0 / 0.9 - 1.0);
    // ---- prop phase: wave per row, lane = channel ----
    int gid = blockIdx.x * blockDim.x + t;
    int i = gid >> 6, c = gid & 63;
    int e0 = rowptr[i], e1 = rowptr[i + 1];
    float acc = 0.0f, wsum = 0.0f;
    for (int base = e0; base < e1; base += 64) {
        int m = e1 - base; if (m > 64) m = 64;
        int   jl = (c < m) ? colIdx[base + c] : 0;
        float yl = (c < m) ? y_e[base + c] : 9.0f;
        float il = (c < m) ? isD[jl] : 0.0f;
        int tt = 0;
        for (; tt + 4 <= m; tt += 4) {
            int j0 = __shfl(jl, tt, 64),     j1 = __shfl(jl, tt + 1, 64);
            int j2 = __shfl(jl, tt + 2, 64), j3 = __shfl(jl, tt + 3, 64);
            float f0 = Fc[(size_t)j0 * 64 + c], f1 = Fc[(size_t)j1 * 64 + c];
            float f2 = Fc[(size_t)j2 * 64 + c], f3 = Fc[(size_t)j3 * 64 + c];
            float s0 = scad_w(__shfl(yl, tt, 64),     lamc);
            float s1 = scad_w(__shfl(yl, tt + 1, 64), lamc);
            float s2 = scad_w(__shfl(yl, tt + 2, 64), lamc);
            float s3 = scad_w(__shfl(yl, tt + 3, 64), lamc);
            wsum += s0 + s1 + s2 + s3;
            acc += s0 * __shfl(il, tt, 64) * f0 + s1 * __shfl(il, tt + 1, 64) * f1
                 + s2 * __shfl(il, tt + 2, 64) * f2 + s3 * __shfl(il, tt + 3, 64) * f3;
        }
        for (; tt < m; tt++) {
            int   j = __shfl(jl, tt, 64);
            float y = __shfl(yl, tt, 64);
            float w = scad_w(y, lamc);
            wsum += w;
            acc += w * __shfl(il, tt, 64) * Fc[(size_t)j * 64 + c];
        }
    }
    float Q = wsum / D[i] + lam;
    Fout[(size_t)i * 64 + c] = (isD[i] * acc + lam * F0[(size_t)i * 64 + c]) / Q;
}

// ---------------------------------------------------------------------------
extern "C" void kernel_launch(void* const* d_in, const int* in_sizes, int n_in,
                              void* d_out, int out_size, void* d_ws, size_t ws_size,
                              hipStream_t stream) {
    const float* A      = (const float*)d_in[0];
    const float* X      = (const float*)d_in[1];
    const float* W1     = (const float*)d_in[2];
    const float* b1     = (const float*)d_in[3];
    const float* W2     = (const float*)d_in[4];
    const float* b2     = (const float*)d_in[5];
    const float* lg0    = (const float*)d_in[6];
    const float* rdec   = (const float*)d_in[7];
    const float* ralpha = (const float*)d_in[8];
    float* out = (float*)d_out;

    char* w = (char*)d_ws;
    size_t off = 0;
    auto carve = [&](size_t bytes) -> char* {
        char* p = w + off;
        off += (bytes + 255) & ~(size_t)255;
        return p;
    };
    int*      rowcnt = (int*)carve(N_NODES * 4);
    int*      rowptr = (int*)carve((N_NODES + 16) * 4);
    int*      colIdx = (int*)carve(MAXE * 4);
    float*    y_e    = (float*)carve(MAXE * 4);
    unsigned* hist   = (unsigned*)carve(NBINS * 4);
    float*    D      = (float*)carve(N_NODES * 4);
    float*    isD    = (float*)carve(N_NODES * 4);
    float*    Fu     = (float*)carve((size_t)N_NODES * 64 * 4);
    float*    H1     = (float*)carve((size_t)N_NODES * H_DIM * 4);   // 4 MB
    float*    part   = (float*)carve((size_t)KSPLIT * N_NODES * H_DIM * 4); // 16 MB
    float*    F0     = (float*)carve((size_t)N_NODES * 64 * 4);
    float*    FcA    = (float*)carve((size_t)N_NODES * 64 * 4);
    float*    FcB    = (float*)carve((size_t)N_NODES * 64 * 4);
    int*      tmpcols = (int*)part;   // dead before GEMMs

    // CSR build: one pass over A + tiny scan/compact.
    k_degfill<<<dim3(N_NODES), dim3(256), 0, stream>>>(A, tmpcols, rowcnt, D, isD);
    k_scan<<<dim3(1), dim3(1024), 0, stream>>>(rowcnt, rowptr);
    k_compact<<<dim3(N_NODES), dim3(64), 0, stream>>>(tmpcols, rowcnt, rowptr, colIdx);

    // MLP: H1 = relu(X@W1 + b1) via K-split-4; F0 = H1@W2 + b2
    k_gemm1_part<<<dim3(H_DIM / 64, N_NODES / 64, KSPLIT), dim3(256), 0, stream>>>(X, W1, part);
    k_fuse1<<<dim3(N_NODES * H_DIM / 4 / 256), dim3(256), 0, stream>>>(part, b1, H1);
    k_gemm2<<<dim3(1, N_NODES / 64), dim3(256), 0, stream>>>(H1, W2, b2, F0);

    const float* fin = F0;
    float* fouts[4] = {FcA, FcB, FcA, out};
    for (int k = 0; k < 4; k++) {
        k_norm<<<dim3(1024), dim3(256), 0, stream>>>(fin, isD, Fu, hist);
        k_edgehist<<<dim3(1024), dim3(256), 0, stream>>>(Fu, rowptr, colIdx, y_e, hist);
        k_propq<<<dim3(1024), dim3(256), 0, stream>>>(hist, rowptr, colIdx, y_e, fin, F0,
                                                      D, isD, lg0, rdec, ralpha, k, fouts[k]);
        fin = fouts[k];
    }
}